// Round 5
// baseline (879.976 us; speedup 1.0000x reference)
//
#include <hip/hip_runtime.h>
#include <hip/hip_bf16.h>

typedef unsigned int uint32;
using short8 = __attribute__((ext_vector_type(8))) short;
using ushort4_t = __attribute__((ext_vector_type(4))) unsigned short;
using f32x4  = __attribute__((ext_vector_type(4))) float;

#define B_ 32
#define C_ 256
#define M_ 4096
#define MATF 2097152      // elements per 32-batch matrix set (32*256*256)

__device__ inline ushort f2bf(float f) {
  __hip_bfloat16 h = __float2bfloat16(f);
  return __builtin_bit_cast(unsigned short, h);
}
__device__ inline float bf2f(ushort u) {
  uint32 v = ((uint32)u) << 16;
  return __builtin_bit_cast(float, v);
}

// ---------------------------------------------------------------------------
// covpool partial (round-3 proven form): slice s of Gram G[b] = X X^T over
// k = s*512..+512. One block = full 256x256 output from one shared LDS panel.
// grid 256 (32 b x 8 s), 1024 threads (16 waves, each a 64x64 quadrant).
// fp32 partials, coalesced-ish 4B stores.
// ---------------------------------------------------------------------------
__global__ __launch_bounds__(1024)
void covpool_kernel(const float* __restrict__ x, float* __restrict__ parts,
                    float* __restrict__ rs) {
  const int bid = blockIdx.x;
  const int b = bid >> 3, s = bid & 7;
  const int kb = s * 512;
  const float* Xb = x + (size_t)b * C_ * M_;
  float* P = parts + (size_t)s * MATF + ((size_t)b << 16);

  __shared__ ushort As[256 * 64];   // 32 KB

  const int t    = threadIdx.x;
  const int lane = t & 63;
  const int w    = t >> 6;            // 0..15
  const int wr   = w >> 2, wc = w & 3;
  const int row  = t >> 2;            // 0..255
  const int ch   = t & 3;             // 16-float source chunk

  float rsum = 0.f;
  f32x4 acc[4][4];
#pragma unroll
  for (int m = 0; m < 4; ++m)
#pragma unroll
    for (int n = 0; n < 4; ++n) acc[m][n] = f32x4{0.f, 0.f, 0.f, 0.f};

  const int swzbase = (row & 7) << 4;
  char* wbase = (char*)As + row * 128;

  for (int k0 = kb; k0 < kb + 512; k0 += 64) {
    __syncthreads();
    const float* src = Xb + (size_t)row * M_ + k0 + ch * 16;
    const float4 v0 = ((const float4*)src)[0];
    const float4 v1 = ((const float4*)src)[1];
    const float4 v2 = ((const float4*)src)[2];
    const float4 v3 = ((const float4*)src)[3];
    rsum += v0.x + v0.y + v0.z + v0.w + v1.x + v1.y + v1.z + v1.w +
            v2.x + v2.y + v2.z + v2.w + v3.x + v3.y + v3.z + v3.w;
    short8 h0, h1;
    h0[0] = (short)f2bf(v0.x); h0[1] = (short)f2bf(v0.y);
    h0[2] = (short)f2bf(v0.z); h0[3] = (short)f2bf(v0.w);
    h0[4] = (short)f2bf(v1.x); h0[5] = (short)f2bf(v1.y);
    h0[6] = (short)f2bf(v1.z); h0[7] = (short)f2bf(v1.w);
    h1[0] = (short)f2bf(v2.x); h1[1] = (short)f2bf(v2.y);
    h1[2] = (short)f2bf(v2.z); h1[3] = (short)f2bf(v2.w);
    h1[4] = (short)f2bf(v3.x); h1[5] = (short)f2bf(v3.y);
    h1[6] = (short)f2bf(v3.z); h1[7] = (short)f2bf(v3.w);
    const int c0 = ch * 2;
    *(short8*)(wbase + ((c0 * 16) ^ swzbase))       = h0;
    *(short8*)(wbase + (((c0 + 1) * 16) ^ swzbase)) = h1;
    __syncthreads();
#pragma unroll
    for (int kk = 0; kk < 2; ++kk) {
      short8 af[4], bfr[4];
      const int slot = kk * 4 + (lane >> 4);
#pragma unroll
      for (int m = 0; m < 4; ++m) {
        const int ar = wr * 64 + m * 16 + (lane & 15);
        af[m] = *(const short8*)((const char*)As + ar * 128 + ((slot * 16) ^ ((ar & 7) << 4)));
      }
#pragma unroll
      for (int n = 0; n < 4; ++n) {
        const int br = wc * 64 + n * 16 + (lane & 15);
        bfr[n] = *(const short8*)((const char*)As + br * 128 + ((slot * 16) ^ ((br & 7) << 4)));
      }
#pragma unroll
      for (int m = 0; m < 4; ++m)
#pragma unroll
        for (int n = 0; n < 4; ++n)
          acc[m][n] = __builtin_amdgcn_mfma_f32_16x16x32_bf16(af[m], bfr[n], acc[m][n], 0, 0, 0);
    }
  }

  rsum += __shfl_xor(rsum, 1);
  rsum += __shfl_xor(rsum, 2);
  if (ch == 0) rs[b * 2048 + s * 256 + row] = rsum;

#pragma unroll
  for (int m = 0; m < 4; ++m)
#pragma unroll
    for (int n = 0; n < 4; ++n)
#pragma unroll
      for (int r = 0; r < 4; ++r) {
        const int lr = wr * 64 + m * 16 + ((lane >> 4) * 4) + r;
        const int lc = wc * 64 + n * 16 + (lane & 15);
        P[(size_t)lr * C_ + lc] = acc[m][n][r];
      }
}

// ---------------------------------------------------------------------------
// trace from partials: n = sum_i (G_ii/M - mu_i^2); invn, sqrtn
// ---------------------------------------------------------------------------
__global__ __launch_bounds__(256)
void trace_kernel(const float* __restrict__ parts, const float* __restrict__ rs,
                  float* __restrict__ invn, float* __restrict__ sqrtn) {
  const int b = blockIdx.x;
  const int i = threadIdx.x;
  const float invM = 1.0f / (float)M_;
  float d = 0.f, m = 0.f;
#pragma unroll
  for (int s = 0; s < 8; ++s) {
    d += parts[(size_t)s * MATF + ((size_t)b << 16) + (size_t)i * 257];
    m += rs[b * 2048 + s * 256 + i];
  }
  const float mu = m * invM;
  float v = d * invM - mu * mu;
#pragma unroll
  for (int o = 32; o > 0; o >>= 1) v += __shfl_xor(v, o);
  __shared__ float wsum[4];
  if ((i & 63) == 0) wsum[i >> 6] = v;
  __syncthreads();
  if (i == 0) {
    const float n = wsum[0] + wsum[1] + wsum[2] + wsum[3];
    invn[b]  = 1.0f / n;
    sqrtn[b] = sqrtf(n);
  }
}

// ---------------------------------------------------------------------------
// reduceprep: cov = (sum_s p_s)/M - mu mu^T (never stored);
// E0 = cov * invn (bf16, trace-normalized)
// ---------------------------------------------------------------------------
__global__ __launch_bounds__(256)
void reduceprep_kernel(const float* __restrict__ parts, const float* __restrict__ rs,
                       const float* __restrict__ invn, ushort* __restrict__ E0) {
  const int idx = blockIdx.x * 256 + threadIdx.x;   // 524288 float4
  const int b   = idx >> 14;
  const int rem = idx & 16383;
  const int i   = rem >> 6;
  const int j   = (rem & 63) * 4;
  const float invM = 1.0f / (float)M_;
  const float4* p4 = (const float4*)parts;

  float4 g = {0.f, 0.f, 0.f, 0.f};
  float  mi = 0.f;
  float4 mj = {0.f, 0.f, 0.f, 0.f};
#pragma unroll
  for (int s = 0; s < 8; ++s) {
    const float4 gs = p4[(size_t)s * (MATF / 4) + idx];
    g.x += gs.x; g.y += gs.y; g.z += gs.z; g.w += gs.w;
    const float* rrow = rs + b * 2048 + s * 256;
    mi += rrow[i];
    const float4 ms = *(const float4*)(rrow + j);
    mj.x += ms.x; mj.y += ms.y; mj.z += ms.z; mj.w += ms.w;
  }
  mi *= invM;
  const float in = invn[b];
  ushort4_t ev;
  ev[0] = f2bf((g.x * invM - mi * (mj.x * invM)) * in);
  ev[1] = f2bf((g.y * invM - mi * (mj.y * invM)) * in);
  ev[2] = f2bf((g.z * invM - mi * (mj.z * invM)) * in);
  ev[3] = f2bf((g.w * invM - mi * (mj.w * invM)) * in);
  ((ushort4_t*)E0)[idx] = ev;
}

// ---------------------------------------------------------------------------
// ns_kernel: persistent per-batch Newton-Schulz chain + matvec chain + MLP.
// grid 32 x 1024 (16 waves). All matrices bf16 in global (XCD-L2-resident);
// fragments read directly from L2 (no LDS staging). Per iteration k=0..3:
//   U  = 1.5 E - 0.5 E@E
//   E' = 1.5 U - 0.5 U@E
// w-chain: w_{k+1} = 1.5 w_k - 0.5 E_k w_k (k=0..4), then v = sqrtn * E0 w5,
// then the 2-layer MLP -> a[b][c].
// ---------------------------------------------------------------------------
__device__ __forceinline__ void mm_unit(const ushort* __restrict__ Ap,
                                        const ushort* __restrict__ Bp,
                                        ushort* __restrict__ Op,
                                        int R, int Cc, int lane) {
  f32x4 acc[4][4];
#pragma unroll
  for (int m = 0; m < 4; ++m)
#pragma unroll
    for (int n = 0; n < 4; ++n) acc[m][n] = f32x4{0.f, 0.f, 0.f, 0.f};

#pragma unroll 1
  for (int ks = 0; ks < 8; ++ks) {
    const int ko = ks * 32 + (lane >> 4) * 8;
    short8 af[4], bfm[4];
#pragma unroll
    for (int m = 0; m < 4; ++m)
      af[m] = *(const short8*)(Ap + (size_t)(R + m * 16 + (lane & 15)) * 256 + ko);
#pragma unroll
    for (int n = 0; n < 4; ++n)
      bfm[n] = *(const short8*)(Bp + (size_t)(Cc + n * 16 + (lane & 15)) * 256 + ko);
#pragma unroll
    for (int m = 0; m < 4; ++m)
#pragma unroll
      for (int n = 0; n < 4; ++n)
        acc[m][n] = __builtin_amdgcn_mfma_f32_16x16x32_bf16(af[m], bfm[n], acc[m][n], 0, 0, 0);
  }

#pragma unroll
  for (int m = 0; m < 4; ++m)
#pragma unroll
    for (int n = 0; n < 4; ++n)
#pragma unroll
      for (int r = 0; r < 4; ++r) {
        const int lr = R + m * 16 + ((lane >> 4) * 4) + r;
        const int lc = Cc + n * 16 + (lane & 15);
        const float o = 1.5f * bf2f(Ap[(size_t)lr * 256 + lc]) - 0.5f * acc[m][n][r];
        Op[(size_t)lr * 256 + lc] = f2bf(o);
      }
}

__global__ __launch_bounds__(1024)
void ns_kernel(const ushort* __restrict__ E0g, ushort* __restrict__ Eag,
               ushort* __restrict__ Ebg, ushort* __restrict__ Ug,
               const float* __restrict__ sqrtn,
               const float* __restrict__ w1, const float* __restrict__ b1,
               const float* __restrict__ w2, const float* __restrict__ b2,
               float* __restrict__ a) {
  const int b = blockIdx.x;
  const size_t off = (size_t)b << 16;
  const ushort* E0 = E0g + off;
  ushort* Ea = Eag + off;
  ushort* Eb = Ebg + off;
  ushort* U  = Ug  + off;

  const int t    = threadIdx.x;
  const int lane = t & 63;
  const int w    = t >> 6;
  const int R    = (w >> 2) * 64;
  const int Cc   = (w & 3) * 64;
  const int c    = t & 255;     // column for matvec work
  const int q    = t >> 8;      // k-quarter for matvec work

  __shared__ float wv[2][C_];
  __shared__ float pw[4][C_];
  __shared__ float vv[C_];
  __shared__ float hh[32];

  if (t < C_) { wv[0][t] = 1.0f / (float)C_; }
  __syncthreads();

  const ushort* Ecur = E0;
  int p = 0;
#pragma unroll 1
  for (int k = 0; k < 5; ++k) {
    // matvec: w_{k+1} = 1.5 w_k - 0.5 * Ecur @ w_k  (Ecur symmetric)
    {
      float part = 0.f;
      const int k0 = q * 64;
#pragma unroll 8
      for (int kk = 0; kk < 64; ++kk)
        part += bf2f(Ecur[(size_t)(k0 + kk) * C_ + c]) * wv[p][k0 + kk];
      pw[q][c] = part;
      __syncthreads();
      if (t < C_) {
        const float s = pw[0][t] + pw[1][t] + pw[2][t] + pw[3][t];
        wv[p ^ 1][t] = 1.5f * wv[p][t] - 0.5f * s;
      }
      __syncthreads();
      p ^= 1;
    }
    if (k < 4) {
      mm_unit(Ecur, Ecur, U, R, Cc, lane);     // U = 1.5E - 0.5 E@E
      __syncthreads();
      ushort* Enext = (k & 1) ? Eb : Ea;
      mm_unit(U, Ecur, Enext, R, Cc, lane);    // E' = 1.5U - 0.5 U@E
      __syncthreads();
      Ecur = Enext;
    }
  }

  // v = sqrtn * (E0 @ w5)
  {
    float part = 0.f;
    const int k0 = q * 64;
#pragma unroll 8
    for (int kk = 0; kk < 64; ++kk)
      part += bf2f(E0[(size_t)(k0 + kk) * C_ + c]) * wv[p][k0 + kk];
    pw[q][c] = part;
    __syncthreads();
    if (t < C_)
      vv[t] = (pw[0][t] + pw[1][t] + pw[2][t] + pw[3][t]) * sqrtn[b];
    __syncthreads();
  }

  // MLP
  if (t < 32) {
    float h = b1[t];
    for (int k = 0; k < C_; ++k) h += w1[t * C_ + k] * vv[k];
    hh[t] = fmaxf(h, 0.0f);
  }
  __syncthreads();
  if (t < C_) {
    float aa = b2[t];
#pragma unroll
    for (int o = 0; o < 32; ++o) aa += w2[t * 32 + o] * hh[o];
    a[b * C_ + t] = 1.0f / (1.0f + expf(-aa));
  }
}

// ---------------------------------------------------------------------------
// scale: out = a[b][c] * x
// ---------------------------------------------------------------------------
__global__ __launch_bounds__(256)
void scale_kernel(const float* __restrict__ x, const float* __restrict__ a,
                  float* __restrict__ out) {
  const int stride = gridDim.x * blockDim.x;
  const int n4 = B_ * C_ * M_ / 4;   // 8388608
  for (int i = blockIdx.x * blockDim.x + threadIdx.x; i < n4; i += stride) {
    const float4 v = ((const float4*)x)[i];
    const float s = a[i >> 10];
    float4 o = { v.x * s, v.y * s, v.z * s, v.w * s };
    ((float4*)out)[i] = o;
  }
}

// ---------------------------------------------------------------------------
extern "C" void kernel_launch(void* const* d_in, const int* in_sizes, int n_in,
                              void* d_out, int out_size, void* d_ws, size_t ws_size,
                              hipStream_t stream) {
  const float* x  = (const float*)d_in[0];
  const float* w1 = (const float*)d_in[1];
  const float* b1 = (const float*)d_in[2];
  const float* w2 = (const float*)d_in[3];
  const float* b2 = (const float*)d_in[4];
  float* out = (float*)d_out;

  float* ws = (float*)d_ws;
  float* parts = ws;                              // 8*MATF fp32 (64 MB)
  float* rs    = ws + 8 * (size_t)MATF;           // 32*2048 fp32
  float* invn  = rs + 65536;
  float* sqrtn = invn + 32;
  float* a     = sqrtn + 32;                      // 32*256
  ushort* E0 = (ushort*)(a + 8192);               // each MATF ushorts (4 MB)
  ushort* Ea = E0 + (size_t)MATF;
  ushort* Eb = Ea + (size_t)MATF;
  ushort* U  = Eb + (size_t)MATF;

  covpool_kernel<<<256, 1024, 0, stream>>>(x, parts, rs);
  trace_kernel<<<32, 256, 0, stream>>>(parts, rs, invn, sqrtn);
  reduceprep_kernel<<<2048, 256, 0, stream>>>(parts, rs, invn, E0);
  ns_kernel<<<32, 1024, 0, stream>>>(E0, Ea, Eb, U, sqrtn, w1, b1, w2, b2, a);
  scale_kernel<<<4096, 256, 0, stream>>>(x, a, out);
}